// Round 4
// baseline (475.847 us; speedup 1.0000x reference)
//
#include <hip/hip_runtime.h>
#include <hip/hip_bf16.h>

// GCN pipeline on MI355X — MFMA bf16 GEMMs, fp32 accumulate/aggregation.
// R4: fuse fp32->bf16 x-conversion into GEMM1 staging (kills cvtx_k, 76us);
//     fuse final W_o1/W_o2 layers into one MFMA kernel writing out[N,2] (kills out_k).
//
//   Wt* = bf16(W^T) (B-frag wants k-contiguous)  (wtr_k x3)
//   CSR build (shared by both convs)
//   hbf  = leaky(x @ W_in + b_in)       bf16     (mgemm MODE=2 ASRC=1, K=239->256)
//   bufF = hbf @ W_g                    f32      (mgemm MODE=0, K=128)
//   hbf  = agg(bufF) + b_g              bf16     (agg_k)
//   bufF = hbf @ W_g ; hbf = agg+b_g             (conv 2)
//   out  = leaky(hbf @ W_o1 + b_o1) @ W_o2 + b_o2  (mgemm MODE=3, fused epilogue)

typedef __attribute__((ext_vector_type(8))) __bf16 bf16x8;
typedef __attribute__((ext_vector_type(4))) float f32x4;

// W [K][128] f32 -> Wt [128][Kp] bf16 (transpose + convert, zero-pad k>=K)
__global__ __launch_bounds__(256) void wtr_k(const float* __restrict__ W, ushort* __restrict__ Wt,
                                             int K, int Kp) {
  int idx = blockIdx.x * 256 + threadIdx.x;
  if (idx >= 128 * Kp) return;
  int n = idx / Kp, k = idx % Kp;
  float v = (k < K) ? W[(size_t)k * 128 + n] : 0.f;
  __hip_bfloat16 h = __float2bfloat16(v);
  Wt[idx] = *(ushort*)&h;
}

// ---------------- CSR build ----------------

__global__ __launch_bounds__(256) void zero_k(int* __restrict__ p, int n) {
  int i = blockIdx.x * 256 + threadIdx.x;
  if (i < n) p[i] = 0;
}

__global__ __launch_bounds__(256) void hist_k(const int* __restrict__ dst, int* __restrict__ cnt, int E) {
  int e = blockIdx.x * 256 + threadIdx.x;
  if (e < E) atomicAdd(&cnt[dst[e]], 1);
}

__global__ __launch_bounds__(256) void dinv_k(const int* __restrict__ cnt, float* __restrict__ dinv, int N) {
  int i = blockIdx.x * 256 + threadIdx.x;
  if (i < N) dinv[i] = rsqrtf((float)cnt[i] + 1.0f);
}

__global__ __launch_bounds__(256) void scan1_k(const int* __restrict__ cnt, int* __restrict__ rp,
                                               int* __restrict__ bsum, int N) {
  __shared__ int sd[256];
  int t = threadIdx.x;
  int base = blockIdx.x * 1024 + t * 4;
  int v0 = (base + 0 < N) ? cnt[base + 0] : 0;
  int v1 = (base + 1 < N) ? cnt[base + 1] : 0;
  int v2 = (base + 2 < N) ? cnt[base + 2] : 0;
  int v3 = (base + 3 < N) ? cnt[base + 3] : 0;
  int ts = v0 + v1 + v2 + v3;
  sd[t] = ts;
  __syncthreads();
  for (int off = 1; off < 256; off <<= 1) {
    int y = (t >= off) ? sd[t - off] : 0;
    __syncthreads();
    sd[t] += y;
    __syncthreads();
  }
  int x = sd[t] - ts;
  if (t == 255) bsum[blockIdx.x] = sd[255];
  if (base + 0 < N) rp[base + 0] = x; x += v0;
  if (base + 1 < N) rp[base + 1] = x; x += v1;
  if (base + 2 < N) rp[base + 2] = x; x += v2;
  if (base + 3 < N) rp[base + 3] = x;
}

__global__ __launch_bounds__(256) void scan2_k(int* __restrict__ bsum, int NB) {
  __shared__ int sd[256];
  int t = threadIdx.x;
  int base = t * 4;
  int v0 = (base + 0 < NB) ? bsum[base + 0] : 0;
  int v1 = (base + 1 < NB) ? bsum[base + 1] : 0;
  int v2 = (base + 2 < NB) ? bsum[base + 2] : 0;
  int v3 = (base + 3 < NB) ? bsum[base + 3] : 0;
  int ts = v0 + v1 + v2 + v3;
  sd[t] = ts;
  __syncthreads();
  for (int off = 1; off < 256; off <<= 1) {
    int y = (t >= off) ? sd[t - off] : 0;
    __syncthreads();
    sd[t] += y;
    __syncthreads();
  }
  int x = sd[t] - ts;
  if (base + 0 < NB) bsum[base + 0] = x; x += v0;
  if (base + 1 < NB) bsum[base + 1] = x; x += v1;
  if (base + 2 < NB) bsum[base + 2] = x; x += v2;
  if (base + 3 < NB) bsum[base + 3] = x;
}

__global__ __launch_bounds__(256) void scan3_k(int* __restrict__ rp, int* __restrict__ pos,
                                               const int* __restrict__ bsum, int N, int E) {
  int i = blockIdx.x * 256 + threadIdx.x;
  if (i < N) {
    int v = rp[i] + bsum[i >> 10];
    rp[i] = v;
    pos[i] = v;
  }
  if (i == 0) rp[N] = E;
}

__global__ __launch_bounds__(256) void fill_k(const int* __restrict__ src, const int* __restrict__ dst,
                                              int* __restrict__ pos, int* __restrict__ col, int E) {
  int e = blockIdx.x * 256 + threadIdx.x;
  if (e < E) {
    int d = dst[e];
    int idx = atomicAdd(&pos[d], 1);
    col[idx] = src[e];
  }
}

// ---------------- MFMA GEMM: C[N,128] = A[N,Kg] @ Wt^T (Wt bf16 [128][Kg]) ----------------
// 128x128 tile, 4 waves, each wave 32 rows x 128 cols = 2x8 tiles of 16x16x32.
// LDS: XOR-swizzled 16B chunks. 64 KB -> 2 blocks/CU.
// ASRC: 0 = A is bf16[N][Kg]; 1 = A is fp32[N][Ka], converted in staging regs (Kg >= Ka pad).
// MODE: 0 = f32 out; 2 = bf16 + bias + leaky; 3 = fused leaky(.+bias)@W2 + b2 -> out[N,2].

template <int MODE, int ASRC>
__global__ __launch_bounds__(256) void mgemm_k(const void* __restrict__ Av,
                                               const ushort* __restrict__ Wt,
                                               const float* __restrict__ bias,
                                               const float* __restrict__ W2,
                                               const float* __restrict__ b2,
                                               void* __restrict__ C, int N, int Kg, int Ka) {
  __shared__ uint4 Al[128 * 16];  // [row][chunk^swz], chunk = 8 bf16 = 16 B
  __shared__ uint4 Wl[128 * 16];
  const int tid = threadIdx.x;
  const int wave = tid >> 6;
  const int lane = tid & 63;
  const int l16 = lane & 15;
  const int quad = lane >> 4;
  const int m0 = blockIdx.x * 128;

  f32x4 acc[2][8] = {};

  const int r_s = tid >> 4;  // staging row within group of 16
  const int j8 = tid & 15;   // staging chunk index
  const int nchunks = Kg >> 7;

  for (int kc = 0; kc < nchunks; ++kc) {
    const int kbase = kc << 7;
    if (kc) __syncthreads();
#pragma unroll
    for (int it = 0; it < 8; ++it) {
      int m = it * 16 + r_s;
      uint4 v;
      if constexpr (ASRC == 0) {
        v = *(const uint4*)((const ushort*)Av + (size_t)(m0 + m) * Kg + kbase + j8 * 8);
      } else {
        int row = m0 + m;
        const float* ap = (const float*)Av + (size_t)row * Ka;
        union { uint4 u; __hip_bfloat16 h[8]; } cv;
#pragma unroll
        for (int j = 0; j < 8; ++j) {
          int c = kbase + j8 * 8 + j;
          float f = (row < N && c < Ka) ? ap[c] : 0.f;
          cv.h[j] = __float2bfloat16(f);
        }
        v = cv.u;
      }
      Al[m * 16 + (j8 ^ r_s)] = v;
    }
#pragma unroll
    for (int it = 0; it < 8; ++it) {
      int n = it * 16 + r_s;
      uint4 v = *(const uint4*)(Wt + (size_t)n * Kg + kbase + j8 * 8);
      Wl[n * 16 + (j8 ^ r_s)] = v;
    }
    __syncthreads();
#pragma unroll
    for (int s = 0; s < 4; ++s) {
      const int j = s * 4 + quad;          // k-chunk this quad reads
      const int swz = j ^ l16;
      bf16x8 a0 = *(const bf16x8*)&Al[(wave * 32 + l16) * 16 + swz];
      bf16x8 a1 = *(const bf16x8*)&Al[(wave * 32 + 16 + l16) * 16 + swz];
#pragma unroll
      for (int c = 0; c < 8; ++c) {
        bf16x8 b = *(const bf16x8*)&Wl[(c * 16 + l16) * 16 + swz];
        acc[0][c] = __builtin_amdgcn_mfma_f32_16x16x32_bf16(a0, b, acc[0][c], 0, 0, 0);
        acc[1][c] = __builtin_amdgcn_mfma_f32_16x16x32_bf16(a1, b, acc[1][c], 0, 0, 0);
      }
    }
  }

  // epilogue: D layout col = c*16 + l16, row = quad*4 + reg (within 16x16 tile)
  float bv[8];
  if (MODE) {
#pragma unroll
    for (int c = 0; c < 8; ++c) bv[c] = bias[c * 16 + l16];
  }

  if constexpr (MODE == 3) {
    float w20[8], w21[8];
#pragma unroll
    for (int c = 0; c < 8; ++c) {
      int colj = c * 16 + l16;
      w20[c] = W2[colj * 2 + 0];
      w21[c] = W2[colj * 2 + 1];
    }
    float bb0 = b2[0], bb1 = b2[1];
#pragma unroll
    for (int r = 0; r < 2; ++r) {
#pragma unroll
      for (int reg = 0; reg < 4; ++reg) {
        float o0 = 0.f, o1 = 0.f;
#pragma unroll
        for (int c = 0; c < 8; ++c) {
          float v = acc[r][c][reg] + bv[c];
          v = v >= 0.f ? v : 0.01f * v;
          o0 = fmaf(v, w20[c], o0);
          o1 = fmaf(v, w21[c], o1);
        }
        o0 += __shfl_xor(o0, 1); o0 += __shfl_xor(o0, 2);
        o0 += __shfl_xor(o0, 4); o0 += __shfl_xor(o0, 8);
        o1 += __shfl_xor(o1, 1); o1 += __shfl_xor(o1, 2);
        o1 += __shfl_xor(o1, 4); o1 += __shfl_xor(o1, 8);
        int row = m0 + wave * 32 + r * 16 + quad * 4 + reg;
        if (l16 == 0 && row < N)
          *(float2*)((float*)C + (size_t)row * 2) = make_float2(o0 + bb0, o1 + bb1);
      }
    }
    return;
  }

#pragma unroll
  for (int r = 0; r < 2; ++r) {
#pragma unroll
    for (int reg = 0; reg < 4; ++reg) {
      int row = m0 + wave * 32 + r * 16 + quad * 4 + reg;
      if (row < N) {
#pragma unroll
        for (int c = 0; c < 8; ++c) {
          float v = acc[r][c][reg];
          if (MODE) {
            v += bv[c];
            v = v >= 0.f ? v : 0.01f * v;
          }
          int colj = c * 16 + l16;
          if (MODE == 2) {
            __hip_bfloat16 h = __float2bfloat16(v);
            ((ushort*)C)[(size_t)row * 128 + colj] = *(ushort*)&h;
          } else {
            ((float*)C)[(size_t)row * 128 + colj] = v;
          }
        }
      }
    }
  }
}

// ---------------- CSR-pull aggregation -> bf16 out ----------------
// O[i] = sum_{e:dst=i} T[src]*dinv[src]*dinv[i] + T[i]*dinv[i]^2 + bias

__global__ __launch_bounds__(256) void agg_k(const float* __restrict__ T, const float* __restrict__ dinv,
                                             const int* __restrict__ rp, const int* __restrict__ col,
                                             const float* __restrict__ bias,
                                             ushort* __restrict__ O, int N) {
  int lane = threadIdx.x & 31;
  int node = blockIdx.x * 8 + (threadIdx.x >> 5);
  if (node >= N) return;
  float di = dinv[node];
  const float4* T4 = (const float4*)T;
  float4 s = T4[(size_t)node * 32 + lane];
  float sw = di * di;
  float ax = s.x * sw, ay = s.y * sw, az = s.z * sw, aw = s.w * sw;
  int e1 = rp[node + 1];
  for (int e = rp[node]; e < e1; ++e) {
    int sc = col[e];
    float w = dinv[sc] * di;
    float4 v = T4[(size_t)sc * 32 + lane];
    ax = fmaf(v.x, w, ax);
    ay = fmaf(v.y, w, ay);
    az = fmaf(v.z, w, az);
    aw = fmaf(v.w, w, aw);
  }
  int c0 = lane * 4;
  union { ushort4 v; __hip_bfloat16 h[4]; } uo;
  uo.h[0] = __float2bfloat16(ax + bias[c0 + 0]);
  uo.h[1] = __float2bfloat16(ay + bias[c0 + 1]);
  uo.h[2] = __float2bfloat16(az + bias[c0 + 2]);
  uo.h[3] = __float2bfloat16(aw + bias[c0 + 3]);
  ((ushort4*)O)[(size_t)node * 32 + lane] = uo.v;
}

// ---------------- launch ----------------

extern "C" void kernel_launch(void* const* d_in, const int* in_sizes, int n_in,
                              void* d_out, int out_size, void* d_ws, size_t ws_size,
                              hipStream_t stream) {
  const float* x = (const float*)d_in[0];
  const int* ei = (const int*)d_in[1];
  const float* W_in = (const float*)d_in[3];
  const float* b_in = (const float*)d_in[4];
  const float* W_g  = (const float*)d_in[5];
  const float* b_g  = (const float*)d_in[6];
  const float* W_o1 = (const float*)d_in[7];
  const float* b_o1 = (const float*)d_in[8];
  const float* W_o2 = (const float*)d_in[9];
  const float* b_o2 = (const float*)d_in[10];

  const int D = in_sizes[4];        // 128
  const int ND = in_sizes[3] / D;   // 239
  const int N = in_sizes[0] / ND;   // 100000
  const int E = in_sizes[2];        // 640000
  const int* src = ei;
  const int* dst = ei + E;

  const int N_pad = ((N + 127) / 128) * 128;
  const size_t np = (size_t)N_pad;
  const int KP1 = 256;  // 239 padded

  // workspace layout (~81 MB)
  float*  bufF = (float*)d_ws;                        // np*128 f32
  ushort* hbf  = (ushort*)((char*)d_ws + np * 512);   // np*128 bf16
  ushort* Wt_in = hbf + np * 128;                     // 128*256 bf16
  ushort* Wt_g  = Wt_in + 128 * 256;                  // 128*128
  ushort* Wt_o1 = Wt_g + 128 * 128;                   // 128*128
  float* dinv = (float*)(Wt_o1 + 128 * 128);
  int* cnt  = (int*)(dinv + N);
  int* rp   = cnt + N;
  int* bsum = rp + (N + 1);
  int* col  = bsum + 1024;

  const int NB = (N + 1023) / 1024;

  // weight transposes
  wtr_k<<<(128 * KP1 + 255) / 256, 256, 0, stream>>>(W_in, Wt_in, ND, KP1);
  wtr_k<<<(128 * 128 + 255) / 256, 256, 0, stream>>>(W_g, Wt_g, 128, 128);
  wtr_k<<<(128 * 128 + 255) / 256, 256, 0, stream>>>(W_o1, Wt_o1, 128, 128);

  // CSR + dinv (shared by both convs)
  zero_k<<<(N + 255) / 256, 256, 0, stream>>>(cnt, N);
  hist_k<<<(E + 255) / 256, 256, 0, stream>>>(dst, cnt, E);
  dinv_k<<<(N + 255) / 256, 256, 0, stream>>>(cnt, dinv, N);
  scan1_k<<<NB, 256, 0, stream>>>(cnt, rp, bsum, N);
  scan2_k<<<1, 256, 0, stream>>>(bsum, NB);
  scan3_k<<<(N + 255) / 256, 256, 0, stream>>>(rp, cnt /*pos*/, bsum, N, E);
  fill_k<<<(E + 255) / 256, 256, 0, stream>>>(src, dst, cnt, col, E);

  const int gblocks = N_pad / 128;
  // h0 = leaky(x @ W_in + b_in) -> bf16   (fp32 A converted in staging)
  mgemm_k<2, 1><<<gblocks, 256, 0, stream>>>(x, Wt_in, b_in, nullptr, nullptr, hbf, N, KP1, ND);
  // conv1
  mgemm_k<0, 0><<<gblocks, 256, 0, stream>>>(hbf, Wt_g, nullptr, nullptr, nullptr, bufF, N, 128, 128);
  agg_k<<<(N + 7) / 8, 256, 0, stream>>>(bufF, dinv, rp, col, b_g, hbf, N);
  // conv2
  mgemm_k<0, 0><<<gblocks, 256, 0, stream>>>(hbf, Wt_g, nullptr, nullptr, nullptr, bufF, N, 128, 128);
  agg_k<<<(N + 7) / 8, 256, 0, stream>>>(bufF, dinv, rp, col, b_g, hbf, N);
  // out = leaky(h @ W_o1 + b_o1) @ W_o2 + b_o2   (fused epilogue)
  mgemm_k<3, 0><<<gblocks, 256, 0, stream>>>(hbf, Wt_o1, b_o1, W_o2, b_o2, d_out, N, 128, 128);
}

// Round 5
// 434.893 us; speedup vs baseline: 1.0942x; 1.0942x over previous
//
#include <hip/hip_runtime.h>
#include <hip/hip_bf16.h>

// GCN pipeline on MI355X — MFMA bf16 GEMMs, fp32 accumulate/aggregation.
// R5: GEMM1's fused fp32->bf16 A-staging now uses aligned-window float4 loads
//     (3x dwordx4 + static cndmask select) instead of 8 scalar dword loads —
//     fixes the 32B-lane-stride coalescing disaster (112us -> ~35us predicted).
//
//   Wt* = bf16(W^T)                              (wtr_k x3)
//   CSR build (shared by both convs)
//   hbf  = leaky(x @ W_in + b_in)       bf16     (mgemm MODE=2 ASRC=1, K=239->256)
//   bufF = hbf @ W_g                    f32      (mgemm MODE=0, K=128)
//   hbf  = agg(bufF) + b_g              bf16     (agg_k)
//   bufF = hbf @ W_g ; hbf = agg+b_g             (conv 2)
//   out  = leaky(hbf @ W_o1 + b_o1) @ W_o2 + b_o2  (mgemm MODE=3, fused epilogue)

typedef __attribute__((ext_vector_type(8))) __bf16 bf16x8;
typedef __attribute__((ext_vector_type(4))) float f32x4;

// W [K][128] f32 -> Wt [128][Kp] bf16 (transpose + convert, zero-pad k>=K)
__global__ __launch_bounds__(256) void wtr_k(const float* __restrict__ W, ushort* __restrict__ Wt,
                                             int K, int Kp) {
  int idx = blockIdx.x * 256 + threadIdx.x;
  if (idx >= 128 * Kp) return;
  int n = idx / Kp, k = idx % Kp;
  float v = (k < K) ? W[(size_t)k * 128 + n] : 0.f;
  __hip_bfloat16 h = __float2bfloat16(v);
  Wt[idx] = *(ushort*)&h;
}

// ---------------- CSR build ----------------

__global__ __launch_bounds__(256) void zero_k(int* __restrict__ p, int n) {
  int i = blockIdx.x * 256 + threadIdx.x;
  if (i < n) p[i] = 0;
}

__global__ __launch_bounds__(256) void hist_k(const int* __restrict__ dst, int* __restrict__ cnt, int E) {
  int e = blockIdx.x * 256 + threadIdx.x;
  if (e < E) atomicAdd(&cnt[dst[e]], 1);
}

__global__ __launch_bounds__(256) void dinv_k(const int* __restrict__ cnt, float* __restrict__ dinv, int N) {
  int i = blockIdx.x * 256 + threadIdx.x;
  if (i < N) dinv[i] = rsqrtf((float)cnt[i] + 1.0f);
}

__global__ __launch_bounds__(256) void scan1_k(const int* __restrict__ cnt, int* __restrict__ rp,
                                               int* __restrict__ bsum, int N) {
  __shared__ int sd[256];
  int t = threadIdx.x;
  int base = blockIdx.x * 1024 + t * 4;
  int v0 = (base + 0 < N) ? cnt[base + 0] : 0;
  int v1 = (base + 1 < N) ? cnt[base + 1] : 0;
  int v2 = (base + 2 < N) ? cnt[base + 2] : 0;
  int v3 = (base + 3 < N) ? cnt[base + 3] : 0;
  int ts = v0 + v1 + v2 + v3;
  sd[t] = ts;
  __syncthreads();
  for (int off = 1; off < 256; off <<= 1) {
    int y = (t >= off) ? sd[t - off] : 0;
    __syncthreads();
    sd[t] += y;
    __syncthreads();
  }
  int x = sd[t] - ts;
  if (t == 255) bsum[blockIdx.x] = sd[255];
  if (base + 0 < N) rp[base + 0] = x; x += v0;
  if (base + 1 < N) rp[base + 1] = x; x += v1;
  if (base + 2 < N) rp[base + 2] = x; x += v2;
  if (base + 3 < N) rp[base + 3] = x;
}

__global__ __launch_bounds__(256) void scan2_k(int* __restrict__ bsum, int NB) {
  __shared__ int sd[256];
  int t = threadIdx.x;
  int base = t * 4;
  int v0 = (base + 0 < NB) ? bsum[base + 0] : 0;
  int v1 = (base + 1 < NB) ? bsum[base + 1] : 0;
  int v2 = (base + 2 < NB) ? bsum[base + 2] : 0;
  int v3 = (base + 3 < NB) ? bsum[base + 3] : 0;
  int ts = v0 + v1 + v2 + v3;
  sd[t] = ts;
  __syncthreads();
  for (int off = 1; off < 256; off <<= 1) {
    int y = (t >= off) ? sd[t - off] : 0;
    __syncthreads();
    sd[t] += y;
    __syncthreads();
  }
  int x = sd[t] - ts;
  if (base + 0 < NB) bsum[base + 0] = x; x += v0;
  if (base + 1 < NB) bsum[base + 1] = x; x += v1;
  if (base + 2 < NB) bsum[base + 2] = x; x += v2;
  if (base + 3 < NB) bsum[base + 3] = x;
}

__global__ __launch_bounds__(256) void scan3_k(int* __restrict__ rp, int* __restrict__ pos,
                                               const int* __restrict__ bsum, int N, int E) {
  int i = blockIdx.x * 256 + threadIdx.x;
  if (i < N) {
    int v = rp[i] + bsum[i >> 10];
    rp[i] = v;
    pos[i] = v;
  }
  if (i == 0) rp[N] = E;
}

__global__ __launch_bounds__(256) void fill_k(const int* __restrict__ src, const int* __restrict__ dst,
                                              int* __restrict__ pos, int* __restrict__ col, int E) {
  int e = blockIdx.x * 256 + threadIdx.x;
  if (e < E) {
    int d = dst[e];
    int idx = atomicAdd(&pos[d], 1);
    col[idx] = src[e];
  }
}

// ---------------- MFMA GEMM: C[N,128] = A[N,Kg] @ Wt^T (Wt bf16 [128][Kg]) ----------------
// 128x128 tile, 4 waves, each wave 32 rows x 128 cols = 2x8 tiles of 16x16x32.
// LDS: XOR-swizzled 16B chunks. 64 KB -> 2 blocks/CU.
// ASRC: 0 = A is bf16[N][Kg]; 1 = A is fp32[N][Ka] (Ka=239), converted in staging via
//       aligned-window float4 loads + static select (rows are 956B, never 16B-aligned).
// MODE: 0 = f32 out; 2 = bf16 + bias + leaky; 3 = fused leaky(.+bias)@W2 + b2 -> out[N,2].

template <int MODE, int ASRC>
__global__ __launch_bounds__(256) void mgemm_k(const void* __restrict__ Av,
                                               const ushort* __restrict__ Wt,
                                               const float* __restrict__ bias,
                                               const float* __restrict__ W2,
                                               const float* __restrict__ b2,
                                               void* __restrict__ C, int N, int Kg, int Ka) {
  __shared__ uint4 Al[128 * 16];  // [row][chunk^swz], chunk = 8 bf16 = 16 B
  __shared__ uint4 Wl[128 * 16];
  const int tid = threadIdx.x;
  const int wave = tid >> 6;
  const int lane = tid & 63;
  const int l16 = lane & 15;
  const int quad = lane >> 4;
  const int m0 = blockIdx.x * 128;

  f32x4 acc[2][8] = {};

  const int r_s = tid >> 4;  // staging row within group of 16
  const int j8 = tid & 15;   // staging chunk index
  const int nchunks = Kg >> 7;

  for (int kc = 0; kc < nchunks; ++kc) {
    const int kbase = kc << 7;
    if (kc) __syncthreads();
#pragma unroll
    for (int it = 0; it < 8; ++it) {
      int m = it * 16 + r_s;
      uint4 v;
      if constexpr (ASRC == 0) {
        v = *(const uint4*)((const ushort*)Av + (size_t)(m0 + m) * Kg + kbase + j8 * 8);
      } else {
        // fp32 source, rows of Ka floats (956 B, misaligned). Aligned-window select:
        // load 3 aligned float4s covering [s&~3, s&~3+12), pick w[ph..ph+7], ph=s&3.
        int row = m0 + m;
        int rc = row < N ? row : N - 1;        // clamp: garbage rows masked at store
        int c0 = kbase + j8 * 8;
        union { uint4 u; __hip_bfloat16 h[8]; } cv;
        if (c0 >= Ka) {
          cv.u = make_uint4(0, 0, 0, 0);       // pure pad chunk (B rows are zero anyway)
        } else {
          const float* xp = (const float*)Av;
          size_t s = (size_t)rc * Ka + c0;
          size_t base = s & ~(size_t)3;
          int ph = (int)(s & 3);
          size_t NT = (size_t)N * Ka;
          if (base + 12 <= NT) {
            const float4* bp = (const float4*)(xp + base);
            float4 f0 = bp[0], f1 = bp[1], f2 = bp[2];
            float w[12] = {f0.x, f0.y, f0.z, f0.w, f1.x, f1.y, f1.z, f1.w,
                           f2.x, f2.y, f2.z, f2.w};
#pragma unroll
            for (int j = 0; j < 8; ++j) {
              // static indices in every arm — no dynamic reg indexing
              float f = ph == 0 ? w[j] : ph == 1 ? w[j + 1] : ph == 2 ? w[j + 2] : w[j + 3];
              cv.h[j] = __float2bfloat16(f);
            }
          } else {
            // buffer-end slow path (a few lanes of the last row's block only)
#pragma unroll
            for (int j = 0; j < 8; ++j) {
              size_t idx = s + j;
              float f = (idx < NT && c0 + j < Ka) ? xp[idx] : 0.f;
              cv.h[j] = __float2bfloat16(f);
            }
          }
        }
        v = cv.u;
      }
      Al[m * 16 + (j8 ^ r_s)] = v;
    }
#pragma unroll
    for (int it = 0; it < 8; ++it) {
      int n = it * 16 + r_s;
      uint4 v = *(const uint4*)(Wt + (size_t)n * Kg + kbase + j8 * 8);
      Wl[n * 16 + (j8 ^ r_s)] = v;
    }
    __syncthreads();
#pragma unroll
    for (int s = 0; s < 4; ++s) {
      const int j = s * 4 + quad;          // k-chunk this quad reads
      const int swz = j ^ l16;
      bf16x8 a0 = *(const bf16x8*)&Al[(wave * 32 + l16) * 16 + swz];
      bf16x8 a1 = *(const bf16x8*)&Al[(wave * 32 + 16 + l16) * 16 + swz];
#pragma unroll
      for (int c = 0; c < 8; ++c) {
        bf16x8 b = *(const bf16x8*)&Wl[(c * 16 + l16) * 16 + swz];
        acc[0][c] = __builtin_amdgcn_mfma_f32_16x16x32_bf16(a0, b, acc[0][c], 0, 0, 0);
        acc[1][c] = __builtin_amdgcn_mfma_f32_16x16x32_bf16(a1, b, acc[1][c], 0, 0, 0);
      }
    }
  }

  // epilogue: D layout col = c*16 + l16, row = quad*4 + reg (within 16x16 tile)
  float bv[8];
  if (MODE) {
#pragma unroll
    for (int c = 0; c < 8; ++c) bv[c] = bias[c * 16 + l16];
  }

  if constexpr (MODE == 3) {
    float w20[8], w21[8];
#pragma unroll
    for (int c = 0; c < 8; ++c) {
      int colj = c * 16 + l16;
      w20[c] = W2[colj * 2 + 0];
      w21[c] = W2[colj * 2 + 1];
    }
    float bb0 = b2[0], bb1 = b2[1];
#pragma unroll
    for (int r = 0; r < 2; ++r) {
#pragma unroll
      for (int reg = 0; reg < 4; ++reg) {
        float o0 = 0.f, o1 = 0.f;
#pragma unroll
        for (int c = 0; c < 8; ++c) {
          float v = acc[r][c][reg] + bv[c];
          v = v >= 0.f ? v : 0.01f * v;
          o0 = fmaf(v, w20[c], o0);
          o1 = fmaf(v, w21[c], o1);
        }
        o0 += __shfl_xor(o0, 1); o0 += __shfl_xor(o0, 2);
        o0 += __shfl_xor(o0, 4); o0 += __shfl_xor(o0, 8);
        o1 += __shfl_xor(o1, 1); o1 += __shfl_xor(o1, 2);
        o1 += __shfl_xor(o1, 4); o1 += __shfl_xor(o1, 8);
        int row = m0 + wave * 32 + r * 16 + quad * 4 + reg;
        if (l16 == 0 && row < N)
          *(float2*)((float*)C + (size_t)row * 2) = make_float2(o0 + bb0, o1 + bb1);
      }
    }
    return;
  }

#pragma unroll
  for (int r = 0; r < 2; ++r) {
#pragma unroll
    for (int reg = 0; reg < 4; ++reg) {
      int row = m0 + wave * 32 + r * 16 + quad * 4 + reg;
      if (row < N) {
#pragma unroll
        for (int c = 0; c < 8; ++c) {
          float v = acc[r][c][reg];
          if (MODE) {
            v += bv[c];
            v = v >= 0.f ? v : 0.01f * v;
          }
          int colj = c * 16 + l16;
          if (MODE == 2) {
            __hip_bfloat16 h = __float2bfloat16(v);
            ((ushort*)C)[(size_t)row * 128 + colj] = *(ushort*)&h;
          } else {
            ((float*)C)[(size_t)row * 128 + colj] = v;
          }
        }
      }
    }
  }
}

// ---------------- CSR-pull aggregation -> bf16 out ----------------
// O[i] = sum_{e:dst=i} T[src]*dinv[src]*dinv[i] + T[i]*dinv[i]^2 + bias

__global__ __launch_bounds__(256) void agg_k(const float* __restrict__ T, const float* __restrict__ dinv,
                                             const int* __restrict__ rp, const int* __restrict__ col,
                                             const float* __restrict__ bias,
                                             ushort* __restrict__ O, int N) {
  int lane = threadIdx.x & 31;
  int node = blockIdx.x * 8 + (threadIdx.x >> 5);
  if (node >= N) return;
  float di = dinv[node];
  const float4* T4 = (const float4*)T;
  float4 s = T4[(size_t)node * 32 + lane];
  float sw = di * di;
  float ax = s.x * sw, ay = s.y * sw, az = s.z * sw, aw = s.w * sw;
  int e1 = rp[node + 1];
  for (int e = rp[node]; e < e1; ++e) {
    int sc = col[e];
    float w = dinv[sc] * di;
    float4 v = T4[(size_t)sc * 32 + lane];
    ax = fmaf(v.x, w, ax);
    ay = fmaf(v.y, w, ay);
    az = fmaf(v.z, w, az);
    aw = fmaf(v.w, w, aw);
  }
  int c0 = lane * 4;
  union { ushort4 v; __hip_bfloat16 h[4]; } uo;
  uo.h[0] = __float2bfloat16(ax + bias[c0 + 0]);
  uo.h[1] = __float2bfloat16(ay + bias[c0 + 1]);
  uo.h[2] = __float2bfloat16(az + bias[c0 + 2]);
  uo.h[3] = __float2bfloat16(aw + bias[c0 + 3]);
  ((ushort4*)O)[(size_t)node * 32 + lane] = uo.v;
}

// ---------------- launch ----------------

extern "C" void kernel_launch(void* const* d_in, const int* in_sizes, int n_in,
                              void* d_out, int out_size, void* d_ws, size_t ws_size,
                              hipStream_t stream) {
  const float* x = (const float*)d_in[0];
  const int* ei = (const int*)d_in[1];
  const float* W_in = (const float*)d_in[3];
  const float* b_in = (const float*)d_in[4];
  const float* W_g  = (const float*)d_in[5];
  const float* b_g  = (const float*)d_in[6];
  const float* W_o1 = (const float*)d_in[7];
  const float* b_o1 = (const float*)d_in[8];
  const float* W_o2 = (const float*)d_in[9];
  const float* b_o2 = (const float*)d_in[10];

  const int D = in_sizes[4];        // 128
  const int ND = in_sizes[3] / D;   // 239
  const int N = in_sizes[0] / ND;   // 100000
  const int E = in_sizes[2];        // 640000
  const int* src = ei;
  const int* dst = ei + E;

  const int N_pad = ((N + 127) / 128) * 128;
  const size_t np = (size_t)N_pad;
  const int KP1 = 256;  // 239 padded

  // workspace layout (~81 MB)
  float*  bufF = (float*)d_ws;                        // np*128 f32
  ushort* hbf  = (ushort*)((char*)d_ws + np * 512);   // np*128 bf16
  ushort* Wt_in = hbf + np * 128;                     // 128*256 bf16
  ushort* Wt_g  = Wt_in + 128 * 256;                  // 128*128
  ushort* Wt_o1 = Wt_g + 128 * 128;                   // 128*128
  float* dinv = (float*)(Wt_o1 + 128 * 128);
  int* cnt  = (int*)(dinv + N);
  int* rp   = cnt + N;
  int* bsum = rp + (N + 1);
  int* col  = bsum + 1024;

  const int NB = (N + 1023) / 1024;

  // weight transposes
  wtr_k<<<(128 * KP1 + 255) / 256, 256, 0, stream>>>(W_in, Wt_in, ND, KP1);
  wtr_k<<<(128 * 128 + 255) / 256, 256, 0, stream>>>(W_g, Wt_g, 128, 128);
  wtr_k<<<(128 * 128 + 255) / 256, 256, 0, stream>>>(W_o1, Wt_o1, 128, 128);

  // CSR + dinv (shared by both convs)
  zero_k<<<(N + 255) / 256, 256, 0, stream>>>(cnt, N);
  hist_k<<<(E + 255) / 256, 256, 0, stream>>>(dst, cnt, E);
  dinv_k<<<(N + 255) / 256, 256, 0, stream>>>(cnt, dinv, N);
  scan1_k<<<NB, 256, 0, stream>>>(cnt, rp, bsum, N);
  scan2_k<<<1, 256, 0, stream>>>(bsum, NB);
  scan3_k<<<(N + 255) / 256, 256, 0, stream>>>(rp, cnt /*pos*/, bsum, N, E);
  fill_k<<<(E + 255) / 256, 256, 0, stream>>>(src, dst, cnt, col, E);

  const int gblocks = N_pad / 128;
  // h0 = leaky(x @ W_in + b_in) -> bf16   (fp32 A converted in staging, window-select loads)
  mgemm_k<2, 1><<<gblocks, 256, 0, stream>>>(x, Wt_in, b_in, nullptr, nullptr, hbf, N, KP1, ND);
  // conv1
  mgemm_k<0, 0><<<gblocks, 256, 0, stream>>>(hbf, Wt_g, nullptr, nullptr, nullptr, bufF, N, 128, 128);
  agg_k<<<(N + 7) / 8, 256, 0, stream>>>(bufF, dinv, rp, col, b_g, hbf, N);
  // conv2
  mgemm_k<0, 0><<<gblocks, 256, 0, stream>>>(hbf, Wt_g, nullptr, nullptr, nullptr, bufF, N, 128, 128);
  agg_k<<<(N + 7) / 8, 256, 0, stream>>>(bufF, dinv, rp, col, b_g, hbf, N);
  // out = leaky(h @ W_o1 + b_o1) @ W_o2 + b_o2   (fused epilogue)
  mgemm_k<3, 0><<<gblocks, 256, 0, stream>>>(hbf, Wt_o1, b_o1, W_o2, b_o2, d_out, N, 128, 128);
}

// Round 6
// 374.393 us; speedup vs baseline: 1.2710x; 1.1616x over previous
//
#include <hip/hip_runtime.h>
#include <hip/hip_bf16.h>

// GCN pipeline on MI355X — MFMA bf16 GEMMs, fp32 accumulate, bf16 dataflow.
// R6: (a) mgemm -> 512 threads (16 waves/CU vs 8: latency overlap, was Occ 16%);
//     (b) reassociate conv: agg(h W) == (agg h) W — aggregate bf16 h first, GEMM after
//         (kills the 51MB f32 intermediate; agg gather bytes halved);
//     (c) per-edge weight precomputed in fill: ew[e] = {src, dinv[src]*dinv[dst]}.
//
//   Wt* = bf16(W^T)                              (wtr_k x3)
//   CSR build + edge weights
//   hA = leaky(x @ W_in + b_in)         bf16     (mgemm MODE=2 ASRC=1, K=239->256)
//   hB = agg(hA)                        bf16     (agg_k)
//   hA = hB @ W_g + b_g                 bf16     (mgemm MODE=1)
//   hB = agg(hA) ; hA = hB @ W_g + b_g           (conv 2)
//   out = leaky(hA @ W_o1 + b_o1) @ W_o2 + b_o2  (mgemm MODE=3)

typedef __attribute__((ext_vector_type(8))) __bf16 bf16x8;
typedef __attribute__((ext_vector_type(4))) float f32x4;

// W [K][128] f32 -> Wt [128][Kp] bf16 (transpose + convert, zero-pad k>=K)
__global__ __launch_bounds__(256) void wtr_k(const float* __restrict__ W, ushort* __restrict__ Wt,
                                             int K, int Kp) {
  int idx = blockIdx.x * 256 + threadIdx.x;
  if (idx >= 128 * Kp) return;
  int n = idx / Kp, k = idx % Kp;
  float v = (k < K) ? W[(size_t)k * 128 + n] : 0.f;
  __hip_bfloat16 h = __float2bfloat16(v);
  Wt[idx] = *(ushort*)&h;
}

// ---------------- CSR build ----------------

__global__ __launch_bounds__(256) void zero_k(int* __restrict__ p, int n) {
  int i = blockIdx.x * 256 + threadIdx.x;
  if (i < n) p[i] = 0;
}

__global__ __launch_bounds__(256) void hist_k(const int* __restrict__ dst, int* __restrict__ cnt, int E) {
  int e = blockIdx.x * 256 + threadIdx.x;
  if (e < E) atomicAdd(&cnt[dst[e]], 1);
}

__global__ __launch_bounds__(256) void dinv_k(const int* __restrict__ cnt, float* __restrict__ dinv, int N) {
  int i = blockIdx.x * 256 + threadIdx.x;
  if (i < N) dinv[i] = rsqrtf((float)cnt[i] + 1.0f);
}

__global__ __launch_bounds__(256) void scan1_k(const int* __restrict__ cnt, int* __restrict__ rp,
                                               int* __restrict__ bsum, int N) {
  __shared__ int sd[256];
  int t = threadIdx.x;
  int base = blockIdx.x * 1024 + t * 4;
  int v0 = (base + 0 < N) ? cnt[base + 0] : 0;
  int v1 = (base + 1 < N) ? cnt[base + 1] : 0;
  int v2 = (base + 2 < N) ? cnt[base + 2] : 0;
  int v3 = (base + 3 < N) ? cnt[base + 3] : 0;
  int ts = v0 + v1 + v2 + v3;
  sd[t] = ts;
  __syncthreads();
  for (int off = 1; off < 256; off <<= 1) {
    int y = (t >= off) ? sd[t - off] : 0;
    __syncthreads();
    sd[t] += y;
    __syncthreads();
  }
  int x = sd[t] - ts;
  if (t == 255) bsum[blockIdx.x] = sd[255];
  if (base + 0 < N) rp[base + 0] = x; x += v0;
  if (base + 1 < N) rp[base + 1] = x; x += v1;
  if (base + 2 < N) rp[base + 2] = x; x += v2;
  if (base + 3 < N) rp[base + 3] = x;
}

__global__ __launch_bounds__(256) void scan2_k(int* __restrict__ bsum, int NB) {
  __shared__ int sd[256];
  int t = threadIdx.x;
  int base = t * 4;
  int v0 = (base + 0 < NB) ? bsum[base + 0] : 0;
  int v1 = (base + 1 < NB) ? bsum[base + 1] : 0;
  int v2 = (base + 2 < NB) ? bsum[base + 2] : 0;
  int v3 = (base + 3 < NB) ? bsum[base + 3] : 0;
  int ts = v0 + v1 + v2 + v3;
  sd[t] = ts;
  __syncthreads();
  for (int off = 1; off < 256; off <<= 1) {
    int y = (t >= off) ? sd[t - off] : 0;
    __syncthreads();
    sd[t] += y;
    __syncthreads();
  }
  int x = sd[t] - ts;
  if (base + 0 < NB) bsum[base + 0] = x; x += v0;
  if (base + 1 < NB) bsum[base + 1] = x; x += v1;
  if (base + 2 < NB) bsum[base + 2] = x; x += v2;
  if (base + 3 < NB) bsum[base + 3] = x;
}

__global__ __launch_bounds__(256) void scan3_k(int* __restrict__ rp, int* __restrict__ pos,
                                               const int* __restrict__ bsum, int N, int E) {
  int i = blockIdx.x * 256 + threadIdx.x;
  if (i < N) {
    int v = rp[i] + bsum[i >> 10];
    rp[i] = v;
    pos[i] = v;
  }
  if (i == 0) rp[N] = E;
}

// bucket-fill edge list with precomputed weight: ew[idx] = {src, bits(dinv[s]*dinv[d])}
__global__ __launch_bounds__(256) void fill_k(const int* __restrict__ src, const int* __restrict__ dst,
                                              const float* __restrict__ dinv,
                                              int* __restrict__ pos, int2* __restrict__ ew, int E) {
  int e = blockIdx.x * 256 + threadIdx.x;
  if (e < E) {
    int d = dst[e];
    int s = src[e];
    int idx = atomicAdd(&pos[d], 1);
    ew[idx] = make_int2(s, __float_as_int(dinv[s] * dinv[d]));
  }
}

// ---------------- MFMA GEMM: C[N,128] = A[N,Kg] @ Wt^T (Wt bf16 [128][Kg]) ----------------
// 128x128 tile, 512 threads / 8 waves, each wave 16 rows x 128 cols (2x8 grid of 16x16x32).
// LDS 64 KB, XOR-swizzled 16B chunks -> 2 blocks/CU = 16 waves/CU.
// ASRC: 0 = A bf16[N][Kg]; 1 = A fp32[N][Ka] converted in staging (aligned-window select).
// MODE: 1 = bf16 + bias; 2 = bf16 + bias + leaky; 3 = fused leaky(.+bias)@W2 + b2 -> out[N,2].

template <int MODE, int ASRC>
__global__ __launch_bounds__(512, 4) void mgemm_k(const void* __restrict__ Av,
                                                  const ushort* __restrict__ Wt,
                                                  const float* __restrict__ bias,
                                                  const float* __restrict__ W2,
                                                  const float* __restrict__ b2,
                                                  void* __restrict__ C, int N, int Kg, int Ka) {
  __shared__ uint4 Al[128 * 16];  // [row][chunk ^ (row&15)]
  __shared__ uint4 Wl[128 * 16];
  const int tid = threadIdx.x;
  const int wave = tid >> 6;     // 0..7
  const int lane = tid & 63;
  const int l16 = lane & 15;
  const int quad = lane >> 4;
  const int m0 = blockIdx.x * 128;

  f32x4 acc[8] = {};

  const int r_s = tid >> 4;      // 0..31 staging row within group of 32
  const int j8 = tid & 15;       // staging chunk index
  const int nch = Kg >> 7;

  for (int kc = 0; kc < nch; ++kc) {
    const int kbase = kc << 7;
    if (kc) __syncthreads();
#pragma unroll
    for (int it = 0; it < 4; ++it) {
      int m = it * 32 + r_s;
      uint4 v;
      if constexpr (ASRC == 0) {
        v = *(const uint4*)((const ushort*)Av + (size_t)(m0 + m) * Kg + kbase + j8 * 8);
      } else {
        // fp32 rows of Ka floats (956 B, misaligned). Aligned-window select.
        // Pad chunks (c0>=Ka) must be zero only to avoid OOB; garbage k in
        // [Ka,Kg) is nullified by Wt's zero rows.
        int row = m0 + m;
        int rc = row < N ? row : N - 1;
        int c0 = kbase + j8 * 8;
        union { uint4 u; __hip_bfloat16 h[8]; } cv;
        if (c0 >= Ka) {
          cv.u = make_uint4(0, 0, 0, 0);
        } else {
          const float* xp = (const float*)Av;
          size_t s = (size_t)rc * Ka + c0;
          size_t base = s & ~(size_t)3;
          int ph = (int)(s & 3);
          size_t NT = (size_t)N * Ka;
          if (base + 12 <= NT) {
            const float4* bp = (const float4*)(xp + base);
            float4 f0 = bp[0], f1 = bp[1], f2 = bp[2];
            float w[12] = {f0.x, f0.y, f0.z, f0.w, f1.x, f1.y, f1.z, f1.w,
                           f2.x, f2.y, f2.z, f2.w};
#pragma unroll
            for (int j = 0; j < 8; ++j) {
              float f = ph == 0 ? w[j] : ph == 1 ? w[j + 1] : ph == 2 ? w[j + 2] : w[j + 3];
              cv.h[j] = __float2bfloat16(f);
            }
          } else {
#pragma unroll
            for (int j = 0; j < 8; ++j) {
              size_t idx = s + j;
              float f = (idx < NT && c0 + j < Ka) ? xp[idx] : 0.f;
              cv.h[j] = __float2bfloat16(f);
            }
          }
        }
        v = cv.u;
      }
      Al[m * 16 + (j8 ^ (m & 15))] = v;
    }
#pragma unroll
    for (int it = 0; it < 4; ++it) {
      int n = it * 32 + r_s;
      uint4 v = *(const uint4*)(Wt + (size_t)n * Kg + kbase + j8 * 8);
      Wl[n * 16 + (j8 ^ (n & 15))] = v;
    }
    __syncthreads();
#pragma unroll
    for (int s = 0; s < 4; ++s) {
      const int j = s * 4 + quad;
      const int swz = j ^ l16;
      bf16x8 a = *(const bf16x8*)&Al[(wave * 16 + l16) * 16 + swz];
#pragma unroll
      for (int c = 0; c < 8; ++c) {
        bf16x8 b = *(const bf16x8*)&Wl[(c * 16 + l16) * 16 + swz];
        acc[c] = __builtin_amdgcn_mfma_f32_16x16x32_bf16(a, b, acc[c], 0, 0, 0);
      }
    }
  }

  // epilogue: D layout col = c*16 + l16, row = quad*4 + reg (within wave's 16 rows)
  float bv[8];
#pragma unroll
  for (int c = 0; c < 8; ++c) bv[c] = bias[c * 16 + l16];

  if constexpr (MODE == 3) {
    float w20[8], w21[8];
#pragma unroll
    for (int c = 0; c < 8; ++c) {
      int colj = c * 16 + l16;
      w20[c] = W2[colj * 2 + 0];
      w21[c] = W2[colj * 2 + 1];
    }
    float bb0 = b2[0], bb1 = b2[1];
#pragma unroll
    for (int reg = 0; reg < 4; ++reg) {
      float o0 = 0.f, o1 = 0.f;
#pragma unroll
      for (int c = 0; c < 8; ++c) {
        float v = acc[c][reg] + bv[c];
        v = v >= 0.f ? v : 0.01f * v;
        o0 = fmaf(v, w20[c], o0);
        o1 = fmaf(v, w21[c], o1);
      }
      o0 += __shfl_xor(o0, 1); o0 += __shfl_xor(o0, 2);
      o0 += __shfl_xor(o0, 4); o0 += __shfl_xor(o0, 8);
      o1 += __shfl_xor(o1, 1); o1 += __shfl_xor(o1, 2);
      o1 += __shfl_xor(o1, 4); o1 += __shfl_xor(o1, 8);
      int row = m0 + wave * 16 + quad * 4 + reg;
      if (l16 == 0 && row < N)
        *(float2*)((float*)C + (size_t)row * 2) = make_float2(o0 + bb0, o1 + bb1);
    }
    return;
  }

#pragma unroll
  for (int reg = 0; reg < 4; ++reg) {
    int row = m0 + wave * 16 + quad * 4 + reg;
    if (row < N) {
#pragma unroll
      for (int c = 0; c < 8; ++c) {
        float v = acc[c][reg] + bv[c];
        if (MODE == 2) v = v >= 0.f ? v : 0.01f * v;
        __hip_bfloat16 h = __float2bfloat16(v);
        ((ushort*)C)[(size_t)row * 128 + c * 16 + l16] = *(ushort*)&h;
      }
    }
  }
}

// ---------------- CSR-pull aggregation, bf16 -> bf16 (no bias) ----------------
// O[i] = sum_{e:dst=i} T[src]*w_e + T[i]*dinv[i]^2 ; 16 lanes/node, 16B/lane.

__global__ __launch_bounds__(256) void agg_k(const ushort* __restrict__ T,
                                             const float* __restrict__ dinv,
                                             const int* __restrict__ rp,
                                             const int2* __restrict__ ew,
                                             ushort* __restrict__ O, int N) {
  int l = threadIdx.x & 15;
  int node = blockIdx.x * 16 + (threadIdx.x >> 4);
  if (node >= N) return;
  float di = dinv[node];
  float dsq = di * di;
  const uint4* T4 = (const uint4*)T;  // row = 16 chunks of 16B (8 bf16)
  float a[8];
  {
    uint4 sv = T4[(size_t)node * 16 + l];
    uint u[4] = {sv.x, sv.y, sv.z, sv.w};
#pragma unroll
    for (int p = 0; p < 4; ++p) {
      a[2 * p + 0] = __uint_as_float(u[p] << 16) * dsq;
      a[2 * p + 1] = __uint_as_float(u[p] & 0xFFFF0000u) * dsq;
    }
  }
  int e1 = rp[node + 1];
  for (int e = rp[node]; e < e1; ++e) {
    int2 pw = ew[e];
    float w = __int_as_float(pw.y);
    uint4 v = T4[(size_t)pw.x * 16 + l];
    uint u[4] = {v.x, v.y, v.z, v.w};
#pragma unroll
    for (int p = 0; p < 4; ++p) {
      a[2 * p + 0] = fmaf(__uint_as_float(u[p] << 16), w, a[2 * p + 0]);
      a[2 * p + 1] = fmaf(__uint_as_float(u[p] & 0xFFFF0000u), w, a[2 * p + 1]);
    }
  }
  union { uint4 v; ushort s[8]; } uo;
#pragma unroll
  for (int j = 0; j < 8; ++j) {
    __hip_bfloat16 h = __float2bfloat16(a[j]);
    uo.s[j] = *(ushort*)&h;
  }
  ((uint4*)O)[(size_t)node * 16 + l] = uo.v;
}

// ---------------- launch ----------------

extern "C" void kernel_launch(void* const* d_in, const int* in_sizes, int n_in,
                              void* d_out, int out_size, void* d_ws, size_t ws_size,
                              hipStream_t stream) {
  const float* x = (const float*)d_in[0];
  const int* ei = (const int*)d_in[1];
  const float* W_in = (const float*)d_in[3];
  const float* b_in = (const float*)d_in[4];
  const float* W_g  = (const float*)d_in[5];
  const float* b_g  = (const float*)d_in[6];
  const float* W_o1 = (const float*)d_in[7];
  const float* b_o1 = (const float*)d_in[8];
  const float* W_o2 = (const float*)d_in[9];
  const float* b_o2 = (const float*)d_in[10];

  const int D = in_sizes[4];        // 128
  const int ND = in_sizes[3] / D;   // 239
  const int N = in_sizes[0] / ND;   // 100000
  const int E = in_sizes[2];        // 640000
  const int* src = ei;
  const int* dst = ei + E;

  const int N_pad = ((N + 127) / 128) * 128;
  const size_t np = (size_t)N_pad;
  const int KP1 = 256;  // 239 padded

  // workspace layout (~60 MB)
  ushort* hA = (ushort*)d_ws;                 // np*128 bf16
  ushort* hB = hA + np * 128;                 // np*128 bf16
  ushort* Wt_in = hB + np * 128;              // 128*256 bf16
  ushort* Wt_g  = Wt_in + 128 * 256;          // 128*128
  ushort* Wt_o1 = Wt_g + 128 * 128;           // 128*128
  float* dinv = (float*)(Wt_o1 + 128 * 128);  // N f32
  int* cnt  = (int*)(dinv + N);
  int* rp   = cnt + N;
  int* bsum = rp + (N + 1);
  int2* ew  = (int2*)(((size_t)(bsum + 1024) + 7) & ~(size_t)7);  // E int2

  const int NB = (N + 1023) / 1024;

  // weight transposes
  wtr_k<<<(128 * KP1 + 255) / 256, 256, 0, stream>>>(W_in, Wt_in, ND, KP1);
  wtr_k<<<(128 * 128 + 255) / 256, 256, 0, stream>>>(W_g, Wt_g, 128, 128);
  wtr_k<<<(128 * 128 + 255) / 256, 256, 0, stream>>>(W_o1, Wt_o1, 128, 128);

  // CSR + dinv + edge weights (shared by both convs)
  zero_k<<<(N + 255) / 256, 256, 0, stream>>>(cnt, N);
  hist_k<<<(E + 255) / 256, 256, 0, stream>>>(dst, cnt, E);
  dinv_k<<<(N + 255) / 256, 256, 0, stream>>>(cnt, dinv, N);
  scan1_k<<<NB, 256, 0, stream>>>(cnt, rp, bsum, N);
  scan2_k<<<1, 256, 0, stream>>>(bsum, NB);
  scan3_k<<<(N + 255) / 256, 256, 0, stream>>>(rp, cnt /*pos*/, bsum, N, E);
  fill_k<<<(E + 255) / 256, 256, 0, stream>>>(src, dst, dinv, cnt, ew, E);

  const int gblocks = N_pad / 128;
  const int ablocks = (N + 15) / 16;
  // h0 = leaky(x @ W_in + b_in) -> hA
  mgemm_k<2, 1><<<gblocks, 512, 0, stream>>>(x, Wt_in, b_in, nullptr, nullptr, hA, N, KP1, ND);
  // conv1: agg first, then GEMM (+bias)
  agg_k<<<ablocks, 256, 0, stream>>>(hA, dinv, rp, ew, hB, N);
  mgemm_k<1, 0><<<gblocks, 512, 0, stream>>>(hB, Wt_g, b_g, nullptr, nullptr, hA, N, 128, 128);
  // conv2
  agg_k<<<ablocks, 256, 0, stream>>>(hA, dinv, rp, ew, hB, N);
  mgemm_k<1, 0><<<gblocks, 512, 0, stream>>>(hB, Wt_g, b_g, nullptr, nullptr, hA, N, 128, 128);
  // out = leaky(hA @ W_o1 + b_o1) @ W_o2 + b_o2
  mgemm_k<3, 0><<<gblocks, 512, 0, stream>>>(hA, Wt_o1, b_o1, W_o2, b_o2, d_out, N, 128, 128);
}

// Round 7
// 365.819 us; speedup vs baseline: 1.3008x; 1.0234x over previous
//
#include <hip/hip_runtime.h>
#include <hip/hip_bf16.h>

// GCN pipeline on MI355X — MFMA bf16 GEMMs, fp32 accumulate, bf16 dataflow.
// R7: GEMM1 rewritten with FLAT-coalesced x staging (contiguous 122KB tile region,
//     lane-adjacent float4 loads) + magic-div row/col decode + LDS 2B scatter.
//     Theory: row-blocked reads of 956B rows hit a ~73us TA line-scatter wall in all
//     3 prior codings; flat streaming is the copy-ubench pattern (~6 TB/s).
//     Also: dinv fused into scan3 (-1 dispatch).

typedef __attribute__((ext_vector_type(8))) __bf16 bf16x8;
typedef __attribute__((ext_vector_type(4))) float f32x4;

// W [K][128] f32 -> Wt [128][Kp] bf16 (transpose + convert, zero-pad k>=K)
__global__ __launch_bounds__(256) void wtr_k(const float* __restrict__ W, ushort* __restrict__ Wt,
                                             int K, int Kp) {
  int idx = blockIdx.x * 256 + threadIdx.x;
  if (idx >= 128 * Kp) return;
  int n = idx / Kp, k = idx % Kp;
  float v = (k < K) ? W[(size_t)k * 128 + n] : 0.f;
  __hip_bfloat16 h = __float2bfloat16(v);
  Wt[idx] = *(ushort*)&h;
}

// ---------------- CSR build ----------------

__global__ __launch_bounds__(256) void zero_k(int* __restrict__ p, int n) {
  int i = blockIdx.x * 256 + threadIdx.x;
  if (i < n) p[i] = 0;
}

__global__ __launch_bounds__(256) void hist_k(const int* __restrict__ dst, int* __restrict__ cnt, int E) {
  int e = blockIdx.x * 256 + threadIdx.x;
  if (e < E) atomicAdd(&cnt[dst[e]], 1);
}

__global__ __launch_bounds__(256) void scan1_k(const int* __restrict__ cnt, int* __restrict__ rp,
                                               int* __restrict__ bsum, int N) {
  __shared__ int sd[256];
  int t = threadIdx.x;
  int base = blockIdx.x * 1024 + t * 4;
  int v0 = (base + 0 < N) ? cnt[base + 0] : 0;
  int v1 = (base + 1 < N) ? cnt[base + 1] : 0;
  int v2 = (base + 2 < N) ? cnt[base + 2] : 0;
  int v3 = (base + 3 < N) ? cnt[base + 3] : 0;
  int ts = v0 + v1 + v2 + v3;
  sd[t] = ts;
  __syncthreads();
  for (int off = 1; off < 256; off <<= 1) {
    int y = (t >= off) ? sd[t - off] : 0;
    __syncthreads();
    sd[t] += y;
    __syncthreads();
  }
  int x = sd[t] - ts;
  if (t == 255) bsum[blockIdx.x] = sd[255];
  if (base + 0 < N) rp[base + 0] = x; x += v0;
  if (base + 1 < N) rp[base + 1] = x; x += v1;
  if (base + 2 < N) rp[base + 2] = x; x += v2;
  if (base + 3 < N) rp[base + 3] = x;
}

__global__ __launch_bounds__(256) void scan2_k(int* __restrict__ bsum, int NB) {
  __shared__ int sd[256];
  int t = threadIdx.x;
  int base = t * 4;
  int v0 = (base + 0 < NB) ? bsum[base + 0] : 0;
  int v1 = (base + 1 < NB) ? bsum[base + 1] : 0;
  int v2 = (base + 2 < NB) ? bsum[base + 2] : 0;
  int v3 = (base + 3 < NB) ? bsum[base + 3] : 0;
  int ts = v0 + v1 + v2 + v3;
  sd[t] = ts;
  __syncthreads();
  for (int off = 1; off < 256; off <<= 1) {
    int y = (t >= off) ? sd[t - off] : 0;
    __syncthreads();
    sd[t] += y;
    __syncthreads();
  }
  int x = sd[t] - ts;
  if (base + 0 < NB) bsum[base + 0] = x; x += v0;
  if (base + 1 < NB) bsum[base + 1] = x; x += v1;
  if (base + 2 < NB) bsum[base + 2] = x; x += v2;
  if (base + 3 < NB) bsum[base + 3] = x;
}

// add block offsets; copy to pos[]; set rp[N]=E; compute dinv from cnt (pre-overwrite)
__global__ __launch_bounds__(256) void scan3_k(int* __restrict__ rp, int* __restrict__ pos,
                                               const int* __restrict__ bsum,
                                               float* __restrict__ dinv, int N, int E) {
  int i = blockIdx.x * 256 + threadIdx.x;
  if (i < N) {
    int c = pos[i];  // pos aliases cnt: still the original count here
    int v = rp[i] + bsum[i >> 10];
    dinv[i] = rsqrtf((float)c + 1.0f);
    rp[i] = v;
    pos[i] = v;
  }
  if (i == 0) rp[N] = E;
}

__global__ __launch_bounds__(256) void fill_k(const int* __restrict__ src, const int* __restrict__ dst,
                                              const float* __restrict__ dinv,
                                              int* __restrict__ pos, int2* __restrict__ ew, int E) {
  int e = blockIdx.x * 256 + threadIdx.x;
  if (e < E) {
    int d = dst[e];
    int s = src[e];
    int idx = atomicAdd(&pos[d], 1);
    ew[idx] = make_int2(s, __float_as_int(dinv[s] * dinv[d]));
  }
}

// ---------------- GEMM1: hA = leaky(x[N,239] @ Wt^T + bias), bf16 out ----------------
// Flat-coalesced staging; LDS Al 128x248 bf16 (496B stride) + Wl 128x72 chunked = 80 KB.

__global__ __launch_bounds__(512, 4) void gemm1_k(const float* __restrict__ x,
                                                  const ushort* __restrict__ Wt,
                                                  const float* __restrict__ bias,
                                                  ushort* __restrict__ C, int N, int Ka,
                                                  unsigned long long M /* ceil(2^40/Ka) */) {
  __shared__ ushort Al[128 * 248];
  __shared__ ushort Wl[128 * 72];
  const int tid = threadIdx.x;
  const int wave = tid >> 6;
  const int lane = tid & 63;
  const int l16 = lane & 15;
  const int quad = lane >> 4;
  const int m0 = blockIdx.x * 128;

  // zero pad cols [239,248) so the pad k-range contributes exact 0
  if (tid < 128) {
    Al[tid * 248 + 239] = 0;
    *(uint4*)&Al[tid * 248 + 240] = make_uint4(0, 0, 0, 0);
  }

  // flat A staging: tile's x bytes are contiguous [m0*Ka, (m0+rows)*Ka)
  {
    int rows = N - m0;
    if (rows > 128) rows = 128;
    const int region = rows * Ka;
    const float* __restrict__ xb = x + (size_t)m0 * Ka;
    const int nv4 = region >> 2;
    for (int i = tid; i < nv4; i += 512) {
      float4 v = ((const float4*)xb)[i];
      int f0 = i * 4;
      float vf[4] = {v.x, v.y, v.z, v.w};
#pragma unroll
      for (int j = 0; j < 4; ++j) {
        int idx = f0 + j;
        uint r = (uint)(((unsigned long long)(uint)idx * M) >> 40);
        uint c = (uint)idx - r * (uint)Ka;
        __hip_bfloat16 h = __float2bfloat16(vf[j]);
        Al[r * 248 + c] = *(ushort*)&h;
      }
    }
    for (int i = (nv4 << 2) + tid; i < region; i += 512) {
      uint r = (uint)(((unsigned long long)(uint)i * M) >> 40);
      uint c = (uint)i - r * (uint)Ka;
      __hip_bfloat16 h = __float2bfloat16(xb[i]);
      Al[r * 248 + c] = *(ushort*)&h;
    }
  }

  f32x4 acc[8] = {};
  const int wn = tid >> 2;
  const int wseg = tid & 3;
#pragma unroll
  for (int kc = 0; kc < 4; ++kc) {
    __syncthreads();
    *(uint4*)&Wl[wn * 72 + wseg * 16] =
        *(const uint4*)(Wt + (size_t)wn * 256 + kc * 64 + wseg * 16);
    *(uint4*)&Wl[wn * 72 + wseg * 16 + 8] =
        *(const uint4*)(Wt + (size_t)wn * 256 + kc * 64 + wseg * 16 + 8);
    __syncthreads();
#pragma unroll
    for (int s = 0; s < 2; ++s) {
      const int koff = kc * 64 + s * 32 + quad * 8;
      bf16x8 a = {};
      if (koff < 248) a = *(const bf16x8*)&Al[(wave * 16 + l16) * 248 + koff];
      const int wof = s * 32 + quad * 8;
#pragma unroll
      for (int c = 0; c < 8; ++c) {
        bf16x8 b = *(const bf16x8*)&Wl[(c * 16 + l16) * 72 + wof];
        acc[c] = __builtin_amdgcn_mfma_f32_16x16x32_bf16(a, b, acc[c], 0, 0, 0);
      }
    }
  }

  float bv[8];
#pragma unroll
  for (int c = 0; c < 8; ++c) bv[c] = bias[c * 16 + l16];
#pragma unroll
  for (int reg = 0; reg < 4; ++reg) {
    int row = m0 + wave * 16 + quad * 4 + reg;
    if (row < N) {
#pragma unroll
      for (int c = 0; c < 8; ++c) {
        float v = acc[c][reg] + bv[c];
        v = v >= 0.f ? v : 0.01f * v;
        __hip_bfloat16 h = __float2bfloat16(v);
        C[(size_t)row * 128 + c * 16 + l16] = *(ushort*)&h;
      }
    }
  }
}

// ---------------- MFMA GEMM (bf16 A, K=128): C = A @ Wt^T ----------------
// MODE: 1 = bf16 + bias; 3 = fused leaky(.+bias)@W2 + b2 -> out[N,2] f32.

template <int MODE>
__global__ __launch_bounds__(512, 4) void mgemm_k(const ushort* __restrict__ A,
                                                  const ushort* __restrict__ Wt,
                                                  const float* __restrict__ bias,
                                                  const float* __restrict__ W2,
                                                  const float* __restrict__ b2,
                                                  void* __restrict__ C, int N) {
  __shared__ uint4 Al[128 * 16];
  __shared__ uint4 Wl[128 * 16];
  const int tid = threadIdx.x;
  const int wave = tid >> 6;
  const int lane = tid & 63;
  const int l16 = lane & 15;
  const int quad = lane >> 4;
  const int m0 = blockIdx.x * 128;

  f32x4 acc[8] = {};
  const int r_s = tid >> 4;
  const int j8 = tid & 15;
#pragma unroll
  for (int it = 0; it < 4; ++it) {
    int m = it * 32 + r_s;
    Al[m * 16 + (j8 ^ (m & 15))] = *(const uint4*)(A + (size_t)(m0 + m) * 128 + j8 * 8);
  }
#pragma unroll
  for (int it = 0; it < 4; ++it) {
    int n = it * 32 + r_s;
    Wl[n * 16 + (j8 ^ (n & 15))] = *(const uint4*)(Wt + (size_t)n * 128 + j8 * 8);
  }
  __syncthreads();
#pragma unroll
  for (int s = 0; s < 4; ++s) {
    const int j = s * 4 + quad;
    const int arow = wave * 16 + l16;
    bf16x8 a = *(const bf16x8*)&Al[arow * 16 + (j ^ (arow & 15))];
#pragma unroll
    for (int c = 0; c < 8; ++c) {
      const int brow = c * 16 + l16;
      bf16x8 b = *(const bf16x8*)&Wl[brow * 16 + (j ^ (brow & 15))];
      acc[c] = __builtin_amdgcn_mfma_f32_16x16x32_bf16(a, b, acc[c], 0, 0, 0);
    }
  }

  float bv[8];
#pragma unroll
  for (int c = 0; c < 8; ++c) bv[c] = bias[c * 16 + l16];

  if constexpr (MODE == 3) {
    float w20[8], w21[8];
#pragma unroll
    for (int c = 0; c < 8; ++c) {
      int colj = c * 16 + l16;
      w20[c] = W2[colj * 2 + 0];
      w21[c] = W2[colj * 2 + 1];
    }
    float bb0 = b2[0], bb1 = b2[1];
#pragma unroll
    for (int reg = 0; reg < 4; ++reg) {
      float o0 = 0.f, o1 = 0.f;
#pragma unroll
      for (int c = 0; c < 8; ++c) {
        float v = acc[c][reg] + bv[c];
        v = v >= 0.f ? v : 0.01f * v;
        o0 = fmaf(v, w20[c], o0);
        o1 = fmaf(v, w21[c], o1);
      }
      o0 += __shfl_xor(o0, 1); o0 += __shfl_xor(o0, 2);
      o0 += __shfl_xor(o0, 4); o0 += __shfl_xor(o0, 8);
      o1 += __shfl_xor(o1, 1); o1 += __shfl_xor(o1, 2);
      o1 += __shfl_xor(o1, 4); o1 += __shfl_xor(o1, 8);
      int row = m0 + wave * 16 + quad * 4 + reg;
      if (l16 == 0 && row < N)
        *(float2*)((float*)C + (size_t)row * 2) = make_float2(o0 + bb0, o1 + bb1);
    }
    return;
  }

#pragma unroll
  for (int reg = 0; reg < 4; ++reg) {
    int row = m0 + wave * 16 + quad * 4 + reg;
    if (row < N) {
#pragma unroll
      for (int c = 0; c < 8; ++c) {
        float v = acc[c][reg] + bv[c];
        __hip_bfloat16 h = __float2bfloat16(v);
        ((ushort*)C)[(size_t)row * 128 + c * 16 + l16] = *(ushort*)&h;
      }
    }
  }
}

// ---------------- CSR-pull aggregation, bf16 -> bf16 ----------------

__global__ __launch_bounds__(256) void agg_k(const ushort* __restrict__ T,
                                             const float* __restrict__ dinv,
                                             const int* __restrict__ rp,
                                             const int2* __restrict__ ew,
                                             ushort* __restrict__ O, int N) {
  int l = threadIdx.x & 15;
  int node = blockIdx.x * 16 + (threadIdx.x >> 4);
  if (node >= N) return;
  float di = dinv[node];
  float dsq = di * di;
  const uint4* T4 = (const uint4*)T;
  float a[8];
  {
    uint4 sv = T4[(size_t)node * 16 + l];
    uint u[4] = {sv.x, sv.y, sv.z, sv.w};
#pragma unroll
    for (int p = 0; p < 4; ++p) {
      a[2 * p + 0] = __uint_as_float(u[p] << 16) * dsq;
      a[2 * p + 1] = __uint_as_float(u[p] & 0xFFFF0000u) * dsq;
    }
  }
  int e1 = rp[node + 1];
  for (int e = rp[node]; e < e1; ++e) {
    int2 pw = ew[e];
    float w = __int_as_float(pw.y);
    uint4 v = T4[(size_t)pw.x * 16 + l];
    uint u[4] = {v.x, v.y, v.z, v.w};
#pragma unroll
    for (int p = 0; p < 4; ++p) {
      a[2 * p + 0] = fmaf(__uint_as_float(u[p] << 16), w, a[2 * p + 0]);
      a[2 * p + 1] = fmaf(__uint_as_float(u[p] & 0xFFFF0000u), w, a[2 * p + 1]);
    }
  }
  union { uint4 v; ushort s[8]; } uo;
#pragma unroll
  for (int j = 0; j < 8; ++j) {
    __hip_bfloat16 h = __float2bfloat16(a[j]);
    uo.s[j] = *(ushort*)&h;
  }
  ((uint4*)O)[(size_t)node * 16 + l] = uo.v;
}

// ---------------- launch ----------------

extern "C" void kernel_launch(void* const* d_in, const int* in_sizes, int n_in,
                              void* d_out, int out_size, void* d_ws, size_t ws_size,
                              hipStream_t stream) {
  const float* x = (const float*)d_in[0];
  const int* ei = (const int*)d_in[1];
  const float* W_in = (const float*)d_in[3];
  const float* b_in = (const float*)d_in[4];
  const float* W_g  = (const float*)d_in[5];
  const float* b_g  = (const float*)d_in[6];
  const float* W_o1 = (const float*)d_in[7];
  const float* b_o1 = (const float*)d_in[8];
  const float* W_o2 = (const float*)d_in[9];
  const float* b_o2 = (const float*)d_in[10];

  const int D = in_sizes[4];        // 128
  const int ND = in_sizes[3] / D;   // 239
  const int N = in_sizes[0] / ND;   // 100000
  const int E = in_sizes[2];        // 640000
  const int* src = ei;
  const int* dst = ei + E;

  const int N_pad = ((N + 127) / 128) * 128;
  const size_t np = (size_t)N_pad;
  const int KP1 = 256;
  const unsigned long long MAGIC = ((1ULL << 40) + (unsigned)ND - 1) / (unsigned)ND;

  ushort* hA = (ushort*)d_ws;                 // np*128 bf16
  ushort* hB = hA + np * 128;                 // np*128 bf16
  ushort* Wt_in = hB + np * 128;              // 128*256 bf16
  ushort* Wt_g  = Wt_in + 128 * 256;          // 128*128
  ushort* Wt_o1 = Wt_g + 128 * 128;           // 128*128
  float* dinv = (float*)(Wt_o1 + 128 * 128);  // N f32
  int* cnt  = (int*)(dinv + N);
  int* rp   = cnt + N;
  int* bsum = rp + (N + 1);
  int2* ew  = (int2*)(((size_t)(bsum + 1024) + 7) & ~(size_t)7);

  const int NB = (N + 1023) / 1024;

  wtr_k<<<(128 * KP1 + 255) / 256, 256, 0, stream>>>(W_in, Wt_in, ND, KP1);
  wtr_k<<<(128 * 128 + 255) / 256, 256, 0, stream>>>(W_g, Wt_g, 128, 128);
  wtr_k<<<(128 * 128 + 255) / 256, 256, 0, stream>>>(W_o1, Wt_o1, 128, 128);

  zero_k<<<(N + 255) / 256, 256, 0, stream>>>(cnt, N);
  hist_k<<<(E + 255) / 256, 256, 0, stream>>>(dst, cnt, E);
  scan1_k<<<NB, 256, 0, stream>>>(cnt, rp, bsum, N);
  scan2_k<<<1, 256, 0, stream>>>(bsum, NB);
  scan3_k<<<(N + 255) / 256, 256, 0, stream>>>(rp, cnt /*pos*/, bsum, dinv, N, E);
  fill_k<<<(E + 255) / 256, 256, 0, stream>>>(src, dst, dinv, cnt, ew, E);

  const int gblocks = N_pad / 128;
  const int ablocks = (N + 15) / 16;
  gemm1_k<<<gblocks, 512, 0, stream>>>(x, Wt_in, b_in, hA, N, ND, MAGIC);
  agg_k<<<ablocks, 256, 0, stream>>>(hA, dinv, rp, ew, hB, N);
  mgemm_k<1><<<gblocks, 512, 0, stream>>>(hB, Wt_g, b_g, nullptr, nullptr, hA, N);
  agg_k<<<ablocks, 256, 0, stream>>>(hA, dinv, rp, ew, hB, N);
  mgemm_k<1><<<gblocks, 512, 0, stream>>>(hB, Wt_g, b_g, nullptr, nullptr, hA, N);
  mgemm_k<3><<<gblocks, 512, 0, stream>>>(hA, Wt_o1, b_o1, W_o2, b_o2, d_out, N);
}